// Round 9
// baseline (1218.564 us; speedup 1.0000x reference)
//
#include <hip/hip_runtime.h>

#define LN2 0.6931471805599453f

constexpr int T = 512, N = 32, C = 4000, S = 64;
constexpr int TN   = T * N;
constexpr int ROWF = 68;          // padded row stride in floats (272B, 16B-aligned)
constexpr int CT   = 16;          // timesteps per LDS chunk
constexpr int NC   = T / CT;      // 32 chunks

// ---------------- Kernel 1: softmax probabilities at the 65 needed classes ---
__global__ __launch_bounds__(256) void k_softmax_probs(
    const float* __restrict__ x, const int* __restrict__ labels,
    float* __restrict__ pp)
{
    int row  = blockIdx.x * 4 + (threadIdx.x >> 6);   // row = t*N + n
    int lane = threadIdx.x & 63;
    const float*  rp  = x + (size_t)row * C;
    const float4* rp4 = reinterpret_cast<const float4*>(rp);

    float m = -INFINITY, s = 0.f;
    #pragma unroll
    for (int k = 0; k < 15; ++k) {                 // 960 of 1000 float4s
        float4 v = rp4[lane + 64 * k];
        float mv = fmaxf(fmaxf(v.x, v.y), fmaxf(v.z, v.w));
        float s4 = __expf(v.x - mv) + __expf(v.y - mv) +
                   __expf(v.z - mv) + __expf(v.w - mv);
        float nm = fmaxf(m, mv);
        s = s * __expf(m - nm) + s4 * __expf(mv - nm);
        m = nm;
    }
    if (lane < 40) {                               // tail 40 float4s
        float4 v = rp4[960 + lane];
        float mv = fmaxf(fmaxf(v.x, v.y), fmaxf(v.z, v.w));
        float s4 = __expf(v.x - mv) + __expf(v.y - mv) +
                   __expf(v.z - mv) + __expf(v.w - mv);
        float nm = fmaxf(m, mv);
        s = s * __expf(m - nm) + s4 * __expf(mv - nm);
        m = nm;
    }
    for (int off = 32; off; off >>= 1) {
        float om = __shfl_xor(m, off), os = __shfl_xor(s, off);
        float nm = fmaxf(m, om);
        s = s * __expf(m - nm) + os * __expf(om - nm);
        m = nm;
    }
    float logZ = m + __logf(s);

    int t = row >> 5, n = row & 31;                // row = t*N + n, N = 32
    int c = labels[n * S + lane];
    float* outp = pp + ((size_t)n * T + t) * ROWF;
    outp[1 + lane] = __expf(rp[c] - logZ);
    if (lane == 0) outp[0] = __expf(rp[0] - logZ);
}

// ---------------- DPP / opaque helpers ---------------------------------------
__device__ __forceinline__ float opq(float x) { asm("" : "+v"(x)); return x; }
__device__ __forceinline__ float movlike(float x) {
    float r; asm("v_mov_b32 %0, %1" : "=v"(r) : "v"(x)); return r;
}
__device__ __forceinline__ float dpp_shr1_zero(float x) {
    int r = __builtin_amdgcn_update_dpp(0, __float_as_int(x),
                                        0x138 /*wave_shr:1*/, 0xf, 0xf, false);
    return __int_as_float(r);
}
template <int MODE>
__device__ __forceinline__ float shr1(float x) {
    if constexpr (MODE == 2) return movlike(x);   // ablate cross-lane
    else return dpp_shr1_zero(x);
}
template <int CTRL>
__device__ __forceinline__ float dpp_max_step(float x) {
    int t = __builtin_amdgcn_update_dpp(__float_as_int(x), __float_as_int(x),
                                        CTRL, 0xf, 0xf, false);
    return fmaxf(x, __int_as_float(t));
}
__device__ __forceinline__ float wave_max_bcast(float x) {
    x = dpp_max_step<0xB1>(x);    // xor 1
    x = dpp_max_step<0x4E>(x);    // xor 2
    x = dpp_max_step<0x141>(x);   // xor 4
    x = dpp_max_step<0x140>(x);   // xor 8
    x = dpp_max_step<0x142>(x);   // row_bcast15
    x = dpp_max_step<0x143>(x);   // row_bcast31 -> lane 63 has wave max
    return __int_as_float(__builtin_amdgcn_readlane(__float_as_int(x), 63));
}
__device__ __forceinline__ void renorm_apply(float g, float& a0, float& a1,
                                             float& aX, int& SH, int target) {
    unsigned bits = __float_as_uint(g);
    int k = (bits == 0u) ? 0 : (target - ((int)(bits >> 23) - 127));
    a0 = ldexpf(a0, k); a1 = ldexpf(a1, k); aX = ldexpf(aX, k);
    SH += k;
}

// ---------------- alpha steps (linear probability domain) --------------------
template <int MODE>
__device__ __forceinline__ void single_step(const float* R, int lane, float skf,
                                            float& a0, float& a1, float& aX) {
    float cb, cl;
    if constexpr (MODE == 1) { cb = opq(0.5f); cl = opq(0.25f); }
    else { cb = R[0]; cl = R[1 + lane]; }
    float p1 = shr1<MODE>(a1);
    float n0 = (a0 + p1) * cb;
    float n1 = fmaf(skf, p1, a0 + a1) * cl;
    float nX = (aX + a1) * cb;
    a0 = n0; a1 = n1; aX = nX;
}

template <int MODE>
__device__ __forceinline__ void pair_step(const float* R0, const float* R1,
    int lane, float skf, float skUf, float skk,
    float& a0, float& a1, float& aX)
{
    float cb1, cl1, cb2, cl2;
    if constexpr (MODE == 1) {
        cb1 = opq(0.5f); cl1 = opq(0.25f); cb2 = opq(0.5f); cl2 = opq(0.25f);
    } else {
        cb1 = R0[0]; cl1 = R0[1 + lane]; cb2 = R1[0]; cl2 = R1[1 + lane];
    }
    float clU = shr1<MODE>(cl1);
    float W   = clU * cl2;
    float A   = cb1 * cb2;
    float B   = clU * cb2;
    float Cc  = A + B;
    float D   = skUf * B;
    float s1  = cb1 + cl1;
    float E   = s1 * cl2;
    float F   = cl1 * cl2;
    float G   = skf * W;
    float H   = fmaf(skf, F + W, cb1 * cl2);
    float I   = skk * W;
    float Y0  = cl1 * cb2;
    float Y1  = s1 * cb2;
    float Y2  = skf * Y0;
    float p1  = shr1<MODE>(a1);
    float p0  = shr1<MODE>(a0);
    float p2  = shr1<MODE>(p1);
    float n0  = fmaf(p0, B, a0 * A) + fmaf(p2, D, p1 * Cc);
    float n1  = fmaf(a1, F, a0 * E) + fmaf(p2, I, fmaf(p1, H, p0 * G));
    float nX  = fmaf(a1, Y1, aX * A) + fmaf(p1, Y2, a0 * Y0);
    a0 = n0; a1 = n1; aX = nX;
}

#define ISSUE(cc) do { if constexpr (MODE != 3) {                             \
    const float* cp_ = bp + (size_t)(cc) * CT * ROWF;                         \
    _Pragma("unroll")                                                         \
    for (int d_ = 0; d_ < CT; ++d_)                                           \
        __builtin_amdgcn_global_load_lds(cp_ + (size_t)d_ * ROWF + lane * 4,  \
                                         &lds[(cc) & 1][d_][0], 16, 0, 0);    \
    } } while (0)
#define WAIT16 do { if constexpr (MODE != 3)                                  \
    asm volatile("s_waitcnt vmcnt(16)" ::: "memory");                         \
    __builtin_amdgcn_sched_barrier(0); } while (0)
#define WAIT0 do { if constexpr (MODE != 3)                                   \
    asm volatile("s_waitcnt vmcnt(0)" ::: "memory");                          \
    __builtin_amdgcn_sched_barrier(0); } while (0)

// 2 composed pairs (4 timesteps) + stale-snapshot renorm (tree off-chain).
#define WIN2(BUF, D0) do {                                                    \
    float gs_ = fmaxf(fmaxf(a0, a1), aX);                                     \
    pair_step<MODE>(&lds[BUF][D0    ][0], &lds[BUF][D0 + 1][0], lane, skf, skUf, skk, a0, a1, aX); \
    pair_step<MODE>(&lds[BUF][D0 + 2][0], &lds[BUF][D0 + 3][0], lane, skf, skUf, skk, a0, a1, aX); \
    renorm_apply(wave_max_bcast(gs_), a0, a1, aX, SH, 100);                   \
} while (0)

#define PROLOGUE_AND_LOOP do {                                                \
    ISSUE(0); ISSUE(1);                                                       \
    WAIT16;                                                                   \
    float i0_, i1_;                                                           \
    if constexpr (MODE == 1) { i0_ = opq(0.5f); i1_ = opq(0.25f); }           \
    else { i0_ = lds[0][0][0]; i1_ = lds[0][0][1]; }                          \
    a0 = (lane == 0) ? i0_ : 0.f;                                             \
    a1 = (lane == 0 && Sl > 0) ? i1_ : 0.f;                                   \
    {                                                                         \
        float gs_ = fmaxf(a0, a1);                                            \
        single_step<MODE>(&lds[0][1][0], lane, skf, a0, a1, aX);              \
        pair_step<MODE>(&lds[0][2][0], &lds[0][3][0], lane, skf, skUf, skk, a0, a1, aX); \
        renorm_apply(wave_max_bcast(gs_), a0, a1, aX, SH, 100);               \
        WIN2(0, 4); WIN2(0, 8); WIN2(0, 12);                                  \
    }                                                                         \
    __builtin_amdgcn_sched_barrier(0);                                        \
    ISSUE(2);                                                                 \
    for (int c = 1; c < NC; ++c) {                                            \
        if (c < NC - 1) WAIT16; else WAIT0;                                   \
        int buf = c & 1;                                                      \
        WIN2(buf, 0); WIN2(buf, 4); WIN2(buf, 8); WIN2(buf, 12);              \
        if (c + 2 < NC) {                                                     \
            __builtin_amdgcn_sched_barrier(0);                                \
            ISSUE(c + 2);                                                     \
        }                                                                     \
    }                                                                         \
} while (0)

// ---------------- Kernel 2 (real): one wave per batch element ---------------
__global__ __launch_bounds__(64) void k_ctc_alpha(
    const float* __restrict__ pp, const int* __restrict__ labels,
    const int* __restrict__ input_len, const int* __restrict__ label_len,
    float* __restrict__ loss_out)
{
    constexpr int MODE = 0;
    __shared__ float lds[2][CT][256];
    const int n = blockIdx.x, lane = threadIdx.x;
    const float* bp = pp + (size_t)n * T * ROWF;
    const int Tin = input_len[n], Sl = label_len[n];

    const int li   = labels[n * S + lane];
    const int lim1 = lane ? labels[n * S + lane - 1] : -1;
    const bool skip_ok = (lane > 0) && (li != 0) && (li != lim1);
    const float skf  = skip_ok ? 1.f : 0.f;
    const float skUf = dpp_shr1_zero(skf);
    const float skk  = skf * skUf;

    asm volatile("s_waitcnt vmcnt(0)" ::: "memory");   // drain scalar-side loads
    __builtin_amdgcn_sched_barrier(0);

    float a0 = 0.f, a1 = 0.f, aX = 0.f;
    int SH = 0;

    if (Tin == T) {
        PROLOGUE_AND_LOOP;
    } else {
        // generic fallback: per-step with freeze masking
#define GSTEP(cc, dd) do {                                                    \
    float cb_ = lds[(cc) & 1][dd][0];                                         \
    float cl_ = lds[(cc) & 1][dd][1 + lane];                                  \
    float p1_ = dpp_shr1_zero(a1);                                            \
    float na0_ = (a0 + p1_) * cb_;                                            \
    float na1_ = fmaf(skf, p1_, a0 + a1) * cl_;                               \
    float naX_ = (aX + a1) * cb_;                                             \
    int t_ = (cc) * CT + (dd);                                                \
    bool act_ = (unsigned)(t_ - 1) < (unsigned)(Tin - 1);                     \
    a0 = act_ ? na0_ : a0;                                                    \
    a1 = act_ ? na1_ : a1;                                                    \
    aX = act_ ? naX_ : aX;                                                    \
    if (((dd) & 3) == 3) {                                                    \
        float g_ = wave_max_bcast(fmaxf(a0, fmaxf(a1, aX)));                  \
        renorm_apply(g_, a0, a1, aX, SH, 100);                                \
    }                                                                         \
} while (0)
        ISSUE(0); ISSUE(1);
        WAIT16;
        a0 = (lane == 0) ? lds[0][0][0] : 0.f;
        a1 = (lane == 0 && Sl > 0) ? lds[0][0][1] : 0.f;
        #pragma unroll
        for (int d = 1; d < CT; ++d) GSTEP(0, d);
        __builtin_amdgcn_sched_barrier(0);
        ISSUE(2);
        for (int c = 1; c < NC; ++c) {
            if (c < NC - 1) WAIT16; else WAIT0;
            #pragma unroll
            for (int d = 0; d < CT; ++d) GSTEP(c, d);
            if (c + 2 < NC) {
                __builtin_amdgcn_sched_barrier(0);
                ISSUE(c + 2);
            }
        }
#undef GSTEP
    }

    float a_last = (Sl >= S) ? __shfl(aX, 63) : __shfl(a0, Sl);
    float a_prev_raw = __shfl(a1, (Sl > 0) ? (Sl - 1) : 0);
    float a_prev = (Sl > 0) ? a_prev_raw : 0.f;
    if (lane == 0) {
        float sum  = a_last + a_prev;
        float ll2  = log2f(sum) - (float)SH;           // log2 P
        float loss = -ll2 * LN2;
        if (!(loss < 5e29f)) loss = 0.f;               // zero_infinity (+NaN)
        loss_out[n] = loss;
    }
}

// ---------------- diagnostic variants (scratch output, dilated) -------------
// MODE 0: full; 1: LDS reads -> opaque consts; 2: chain DPP -> v_mov;
// MODE 3: no DMA, no vmcnt waits (reads stale LDS).
template <int MODE, int REPS>
__global__ __launch_bounds__(64) void k_alpha_var(
    const float* __restrict__ pp, const int* __restrict__ labels,
    const int* __restrict__ label_len, float* __restrict__ scr)
{
    __shared__ float lds[2][CT][256];
    const int n = blockIdx.x, lane = threadIdx.x;
    const float* bp = pp + (size_t)n * T * ROWF;
    const int Sl = label_len[n];

    const int li   = labels[n * S + lane];
    const int lim1 = lane ? labels[n * S + lane - 1] : -1;
    const bool skip_ok = (lane > 0) && (li != 0) && (li != lim1);
    const float skf  = skip_ok ? 1.f : 0.f;
    const float skUf = shr1<MODE>(skf);
    const float skk  = skf * skUf;

    asm volatile("s_waitcnt vmcnt(0)" ::: "memory");
    __builtin_amdgcn_sched_barrier(0);

    float acc = 0.f;
    for (int rep = 0; rep < REPS; ++rep) {
        asm volatile("" ::: "memory");     // no cross-rep CSE/DCE
        float a0 = 0.f, a1 = 0.f, aX = 0.f;
        int SH = 0;
        PROLOGUE_AND_LOOP;
        acc += a0 + a1 + aX + (float)SH;   // keep every rep live
    }
    for (int off = 32; off; off >>= 1) acc += __shfl_xor(acc, off);
    if (lane == 0) scr[n] = acc;
}

// ---------------- Kernel 3: final sum ---------------------------------------
__global__ __launch_bounds__(64) void k_reduce(
    const float* __restrict__ loss, float* __restrict__ out)
{
    int lane = threadIdx.x;
    float v = (lane < N) ? loss[lane] : 0.f;
    for (int off = 32; off; off >>= 1) v += __shfl_xor(v, off);
    if (lane == 0) out[0] = v;
}

extern "C" void kernel_launch(void* const* d_in, const int* in_sizes, int n_in,
                              void* d_out, int out_size, void* d_ws, size_t ws_size,
                              hipStream_t stream) {
    const float* x       = (const float*)d_in[0];
    const int*   labels  = (const int*)d_in[1];
    const int*   in_len  = (const int*)d_in[2];
    const int*   lab_len = (const int*)d_in[3];
    float* out  = (float*)d_out;
    float* pp   = (float*)d_ws;                          // TN*ROWF floats
    float* loss = pp + (size_t)TN * ROWF + 256;          // +1KB pad (DMA over-read)
    float* scr  = loss + N;

    k_softmax_probs<<<TN / 4, 256, 0, stream>>>(x, labels, pp);
    k_ctc_alpha<<<N, 64, 0, stream>>>(pp, labels, in_len, lab_len, loss);
    k_reduce<<<1, 64, 0, stream>>>(loss, out);

    // --- diagnostic ablation (scratch only; remove next round) ---
    k_alpha_var<0,  5><<<N, 64, 0, stream>>>(pp, labels, lab_len, scr);
    k_alpha_var<1, 10><<<N, 64, 0, stream>>>(pp, labels, lab_len, scr + N);
    k_alpha_var<2, 10><<<N, 64, 0, stream>>>(pp, labels, lab_len, scr + 2 * N);
    k_alpha_var<3, 10><<<N, 64, 0, stream>>>(pp, labels, lab_len, scr + 3 * N);
}

// Round 10
// 99.042 us; speedup vs baseline: 12.3035x; 12.3035x over previous
//
#include <hip/hip_runtime.h>

#define LN2 0.6931471805599453f

typedef float f4 __attribute__((ext_vector_type(4)));

constexpr int T = 512, N = 32, C = 4000, S = 64;
constexpr int TN   = T * N;
constexpr int ROWF = 68;          // padded pp row stride (272B)
constexpr int CT   = 16;          // generic-path chunk (timesteps)
constexpr int NC   = T / CT;
constexpr int NPAIR = 256;        // pairs per n (pair p = timesteps 2p,2p+1)
constexpr int PAIRF = 768;        // floats per pair: 3 jblk * 64 lane * 4

// ---------------- DPP helpers ------------------------------------------------
__device__ __forceinline__ float dpp_shr1_zero(float x) {
    int r = __builtin_amdgcn_update_dpp(0, __float_as_int(x),
                                        0x138 /*wave_shr:1*/, 0xf, 0xf, false);
    return __int_as_float(r);
}
template <int CTRL>
__device__ __forceinline__ float dpp_max_step(float x) {
    int t = __builtin_amdgcn_update_dpp(__float_as_int(x), __float_as_int(x),
                                        CTRL, 0xf, 0xf, false);
    return fmaxf(x, __int_as_float(t));
}
__device__ __forceinline__ float wave_max_bcast(float x) {
    x = dpp_max_step<0xB1>(x);    // xor 1
    x = dpp_max_step<0x4E>(x);    // xor 2
    x = dpp_max_step<0x141>(x);   // xor 4
    x = dpp_max_step<0x140>(x);   // xor 8
    x = dpp_max_step<0x142>(x);   // row_bcast15
    x = dpp_max_step<0x143>(x);   // row_bcast31
    return __int_as_float(__builtin_amdgcn_readlane(__float_as_int(x), 63));
}
__device__ __forceinline__ f4 ldexp4(f4 v, int k) {
    v.x = ldexpf(v.x, k); v.y = ldexpf(v.y, k);
    v.z = ldexpf(v.z, k); v.w = ldexpf(v.w, k);
    return v;
}

// ---------------- Kernel 1: softmax probs + pair-composition coefficients ----
// Block = 4 consecutive timesteps of one n. Waves compute p-rows, exchange via
// LDS; odd waves emit the 2-step composed transfer coefficients (12/lane/pair).
__global__ __launch_bounds__(256) void k_softmax_probs(
    const float* __restrict__ x, const int* __restrict__ labels,
    float* __restrict__ pp, float* __restrict__ coef)
{
    __shared__ float lrow[4][72];
    int b = blockIdx.x;
    int n = b & 31, t0 = (b >> 5) << 2;
    int wv = threadIdx.x >> 6, lane = threadIdx.x & 63;
    int t = t0 + wv;
    const float* rp  = x + (size_t)(t * 32 + n) * C;
    const f4*    rp4 = reinterpret_cast<const f4*>(rp);

    float m = -INFINITY, s = 0.f;
    #pragma unroll
    for (int k = 0; k < 15; ++k) {                 // 960 of 1000 f4s
        f4 v = rp4[lane + 64 * k];
        float mv = fmaxf(fmaxf(v.x, v.y), fmaxf(v.z, v.w));
        float s4 = __expf(v.x - mv) + __expf(v.y - mv) +
                   __expf(v.z - mv) + __expf(v.w - mv);
        float nm = fmaxf(m, mv);
        s = s * __expf(m - nm) + s4 * __expf(mv - nm);
        m = nm;
    }
    if (lane < 40) {                               // tail 40 f4s
        f4 v = rp4[960 + lane];
        float mv = fmaxf(fmaxf(v.x, v.y), fmaxf(v.z, v.w));
        float s4 = __expf(v.x - mv) + __expf(v.y - mv) +
                   __expf(v.z - mv) + __expf(v.w - mv);
        float nm = fmaxf(m, mv);
        s = s * __expf(m - nm) + s4 * __expf(mv - nm);
        m = nm;
    }
    for (int off = 32; off; off >>= 1) {
        float om = __shfl_xor(m, off), os = __shfl_xor(s, off);
        float nm = fmaxf(m, om);
        s = s * __expf(m - nm) + os * __expf(om - nm);
        m = nm;
    }
    float logZ = m + __logf(s);

    int c = labels[n * S + lane];
    float cb = __expf(rp[0] - logZ);               // blank prob
    float cl = __expf(rp[c] - logZ);               // label prob (lane = s)

    float* outp = pp + ((size_t)n * T + t) * ROWF; // keep pp (init + fallback)
    outp[1 + lane] = cl;
    if (lane == 0) outp[0] = cb;

    lrow[wv][1 + lane] = cl;
    if (lane == 0) lrow[wv][0] = cb;
    __syncthreads();

    if (wv & 1) {                                  // compose (t-1, t)
        float cb1 = lrow[wv - 1][0], cl1 = lrow[wv - 1][1 + lane];
        float cb2 = cb, cl2 = cl;
        int lim1 = lane ? labels[n * S + lane - 1] : -1;
        float skf  = (lane > 0 && c != 0 && c != lim1) ? 1.f : 0.f;
        float skUf = dpp_shr1_zero(skf);
        float clU  = dpp_shr1_zero(cl1);
        float A  = cb1 * cb2;
        float B  = clU * cb2;
        float Cc = A + B;
        float D  = skUf * B;
        float s1 = cb1 + cl1;
        float E  = s1 * cl2;
        float F  = cl1 * cl2;
        float W  = clU * cl2;
        float G  = skf * W;
        float H  = fmaf(skf, F + W, cb1 * cl2);
        float I  = (skf * skUf) * W;
        float Y0 = cl1 * cb2;
        float Y1 = s1 * cb2;
        float Y2 = skf * Y0;
        int pair = (t0 >> 1) + (wv >> 1);
        f4* dst = (f4*)(coef + ((size_t)n * NPAIR + pair) * PAIRF);
        dst[0 * 64 + lane] = (f4){A, B, Cc, D};
        dst[1 * 64 + lane] = (f4){E, F, G, H};
        dst[2 * 64 + lane] = (f4){I, Y0, Y1, Y2};
    }
}

// ---------------- Kernel 2: alpha recursion ---------------------------------
// One wave per n. Hot path: precomputed pair coefficients, DMA-chunked into
// LDS 2 chunks ahead, batch-ds_read one window (4 pairs = 8 steps) ahead into
// regs; pure-VALU chain; renorm folded into next window's pair0 coefficients.
__global__ __launch_bounds__(64) void k_ctc_alpha(
    const float* __restrict__ pp, const float* __restrict__ coef,
    const int* __restrict__ labels,
    const int* __restrict__ input_len, const int* __restrict__ label_len,
    float* __restrict__ loss_out)
{
    __shared__ f4    ldsH[2][24][64];      // hot: 2 x 8 pairs x 3 jblk -> 48KB
    __shared__ float ldsG[2][CT][256];     // generic fallback: 32KB
    const int n = blockIdx.x, lane = threadIdx.x;
    const int Tin = input_len[n], Sl = label_len[n];
    const float* bp   = pp + (size_t)n * T * ROWF;
    const float* cfgf = coef + (size_t)n * NPAIR * PAIRF;

    const int li   = labels[n * S + lane];
    const int lim1 = lane ? labels[n * S + lane - 1] : -1;
    const float skf = (lane > 0 && li != 0 && li != lim1) ? 1.f : 0.f;

    float a0 = 0.f, a1 = 0.f, aX = 0.f;
    int SH = 0, kf = 0;

#define PAIRC(R0, R1, R2) do {                                                \
    float p1_ = dpp_shr1_zero(a1);                                            \
    float p0_ = dpp_shr1_zero(a0);                                            \
    float p2_ = dpp_shr1_zero(p1_);                                           \
    float n0_ = fmaf(p0_, (R0).y, a0 * (R0).x) + fmaf(p2_, (R0).w, p1_ * (R0).z); \
    float n1_ = fmaf(a1, (R1).y, a0 * (R1).x) +                               \
                fmaf(p2_, (R2).x, fmaf(p1_, (R1).w, p0_ * (R1).z));           \
    float nX_ = fmaf(a1, (R2).z, aX * (R0).x) + fmaf(p1_, (R2).w, a0 * (R2).y); \
    a0 = n0_; a1 = n1_; aX = nX_;                                             \
} while (0)

#define ISSUE(cc) do {                                                        \
    const float* src_ = cfgf + (size_t)(4 + 8 * (cc)) * PAIRF;                \
    float* dst_ = (float*)&ldsH[(cc) & 1][0][0];                              \
    _Pragma("unroll")                                                         \
    for (int i_ = 0; i_ < 24; ++i_)                                           \
        __builtin_amdgcn_global_load_lds(src_ + i_ * 256 + lane * 4,          \
                                         dst_ + i_ * 256, 16, 0, 0);          \
} while (0)

#define DSREAD(DST, BUF, HALF) do {                                           \
    _Pragma("unroll")                                                         \
    for (int q_ = 0; q_ < 4; ++q_)                                            \
        _Pragma("unroll")                                                     \
        for (int j_ = 0; j_ < 3; ++j_)                                        \
            DST[q_ * 3 + j_] = ldsH[BUF][(HALF) * 12 + q_ * 3 + j_][lane];    \
} while (0)

// window = 4 pairs (8 steps). Fold prev k into pair0 coefs (off-chain),
// mid-window max snapshot -> tree (off-chain) -> k for next window.
#define WINDOW(CF) do {                                                       \
    CF[0] = ldexp4(CF[0], kf); CF[1] = ldexp4(CF[1], kf);                     \
    CF[2] = ldexp4(CF[2], kf);                                                \
    SH += kf;                                                                 \
    PAIRC(CF[0], CF[1], CF[2]);                                               \
    PAIRC(CF[3], CF[4], CF[5]);                                               \
    float gs_ = fmaxf(fmaxf(a0, a1), aX);                                     \
    PAIRC(CF[6], CF[7], CF[8]);                                               \
    PAIRC(CF[9], CF[10], CF[11]);                                             \
    {   float g_ = wave_max_bcast(gs_);                                       \
        unsigned b_ = __float_as_uint(g_);                                    \
        kf = (b_ == 0u) ? 0 : (105 - ((int)(b_ >> 23) - 127)); }              \
} while (0)

    if (Tin == T) {
        // ---- prologue: plain loads for t=0,1 and pairs 1..3 ----
        float p00 = bp[0], p01 = bp[1];
        float cb1v = bp[ROWF], cl1v = bp[ROWF + 1 + lane];
        const f4* cfg4 = (const f4*)cfgf;
        f4 pc[9];
        #pragma unroll
        for (int pi = 0; pi < 3; ++pi)
            #pragma unroll
            for (int j = 0; j < 3; ++j)
                pc[pi * 3 + j] = cfg4[(1 + pi) * 192 + j * 64 + lane];
        asm volatile("s_waitcnt vmcnt(0)" ::: "memory");   // drain plain loads
        __builtin_amdgcn_sched_barrier(0);
        ISSUE(0); ISSUE(1);                                // 48 DMA loads out

        a0 = (lane == 0) ? p00 : 0.f;
        a1 = (lane == 0 && Sl > 0) ? p01 : 0.f;
        {   // t = 1
            float p1_ = dpp_shr1_zero(a1);
            float n0_ = (a0 + p1_) * cb1v;
            float n1_ = fmaf(skf, p1_, a0 + a1) * cl1v;
            float nX_ = (aX + a1) * cb1v;
            a0 = n0_; a1 = n1_; aX = nX_;
        }
        PAIRC(pc[0], pc[1], pc[2]);                        // t=2,3
        PAIRC(pc[3], pc[4], pc[5]);                        // t=4,5
        PAIRC(pc[6], pc[7], pc[8]);                        // t=6,7
        {   // direct renorm to prologue level 2^57
            float g_ = wave_max_bcast(fmaxf(fmaxf(a0, a1), aX));
            unsigned b_ = __float_as_uint(g_);
            int k0 = (b_ == 0u) ? 0 : (57 - ((int)(b_ >> 23) - 127));
            a0 = ldexpf(a0, k0); a1 = ldexpf(a1, k0); aX = ldexpf(aX, k0);
            SH += k0; kf = 0;
        }

        f4 cA[12], cB[12];
        asm volatile("s_waitcnt vmcnt(24)" ::: "memory");  // chunk0 landed
        __builtin_amdgcn_sched_barrier(0);
        DSREAD(cA, 0, 0);                                  // window 0 regs
        __builtin_amdgcn_sched_barrier(0);

        for (int c = 0; c < 31; ++c) {
            int buf = c & 1;
            // phase A: window 2c
            DSREAD(cB, buf, 1);                            // window 2c+1 reads
            __builtin_amdgcn_sched_barrier(0);
            asm volatile("s_waitcnt lgkmcnt(12)" ::: "memory");
            __builtin_amdgcn_sched_barrier(0);
            WINDOW(cA);
            // phase B: window 2c+1
            asm volatile("s_waitcnt lgkmcnt(0)" ::: "memory"); // buf reads retired
            __builtin_amdgcn_sched_barrier(0);
            if (c + 2 <= 31) ISSUE(c + 2);                 // overwrite buf
            if (c < 30) { asm volatile("s_waitcnt vmcnt(24)" ::: "memory"); }
            else        { asm volatile("s_waitcnt vmcnt(0)"  ::: "memory"); }
            __builtin_amdgcn_sched_barrier(0);
            DSREAD(cA, buf ^ 1, 0);                        // window 2c+2 reads
            __builtin_amdgcn_sched_barrier(0);
            WINDOW(cB);
        }
        // tail: window 62
        asm volatile("s_waitcnt lgkmcnt(0)" ::: "memory");
        __builtin_amdgcn_sched_barrier(0);
        WINDOW(cA);
    } else {
        // ---- generic fallback: per-step from pp with freeze masking (R7) ----
#define ISSUEG(cc) do {                                                       \
    const float* cp_ = bp + (size_t)(cc) * CT * ROWF;                         \
    _Pragma("unroll")                                                         \
    for (int d_ = 0; d_ < CT; ++d_)                                           \
        __builtin_amdgcn_global_load_lds(cp_ + (size_t)d_ * ROWF + lane * 4,  \
                                         &ldsG[(cc) & 1][d_][0], 16, 0, 0);   \
} while (0)
#define GSTEP(cc, dd) do {                                                    \
    float cb_ = ldsG[(cc) & 1][dd][0];                                        \
    float cl_ = ldsG[(cc) & 1][dd][1 + lane];                                 \
    float p1_ = dpp_shr1_zero(a1);                                            \
    float na0_ = (a0 + p1_) * cb_;                                            \
    float na1_ = fmaf(skf, p1_, a0 + a1) * cl_;                               \
    float naX_ = (aX + a1) * cb_;                                             \
    int t_ = (cc) * CT + (dd);                                                \
    bool act_ = (unsigned)(t_ - 1) < (unsigned)(Tin - 1);                     \
    a0 = act_ ? na0_ : a0;                                                    \
    a1 = act_ ? na1_ : a1;                                                    \
    aX = act_ ? naX_ : aX;                                                    \
    if (((dd) & 3) == 3) {                                                    \
        float g_ = wave_max_bcast(fmaxf(a0, fmaxf(a1, aX)));                  \
        unsigned b_ = __float_as_uint(g_);                                    \
        int k_ = (b_ == 0u) ? 0 : (100 - ((int)(b_ >> 23) - 127));            \
        a0 = ldexpf(a0, k_); a1 = ldexpf(a1, k_); aX = ldexpf(aX, k_);        \
        SH += k_;                                                             \
    }                                                                         \
} while (0)
        asm volatile("s_waitcnt vmcnt(0)" ::: "memory");
        __builtin_amdgcn_sched_barrier(0);
        ISSUEG(0); ISSUEG(1);
        asm volatile("s_waitcnt vmcnt(16)" ::: "memory");
        __builtin_amdgcn_sched_barrier(0);
        a0 = (lane == 0) ? ldsG[0][0][0] : 0.f;
        a1 = (lane == 0 && Sl > 0) ? ldsG[0][0][1] : 0.f;
        #pragma unroll
        for (int d = 1; d < CT; ++d) GSTEP(0, d);
        __builtin_amdgcn_sched_barrier(0);
        ISSUEG(2);
        for (int c = 1; c < NC; ++c) {
            if (c < NC - 1) { asm volatile("s_waitcnt vmcnt(16)" ::: "memory"); }
            else            { asm volatile("s_waitcnt vmcnt(0)"  ::: "memory"); }
            __builtin_amdgcn_sched_barrier(0);
            #pragma unroll
            for (int d = 0; d < CT; ++d) GSTEP(c, d);
            if (c + 2 < NC) {
                __builtin_amdgcn_sched_barrier(0);
                ISSUEG(c + 2);
            }
        }
#undef GSTEP
#undef ISSUEG
    }

    // loss_n = -log(alpha[2*Sl] + alpha[2*Sl-1]) with accumulated 2^SH scale
    float a_last = (Sl >= S) ? __shfl(aX, 63) : __shfl(a0, Sl);
    float a_prev_raw = __shfl(a1, (Sl > 0) ? (Sl - 1) : 0);
    float a_prev = (Sl > 0) ? a_prev_raw : 0.f;
    if (lane == 0) {
        float sum  = a_last + a_prev;
        float ll2  = log2f(sum) - (float)SH;
        float loss = -ll2 * LN2;
        if (!(loss < 5e29f)) loss = 0.f;               // zero_infinity (+NaN)
        loss_out[n] = loss;
    }
#undef WINDOW
#undef DSREAD
#undef ISSUE
#undef PAIRC
}

// ---------------- Kernel 3: final sum ---------------------------------------
__global__ __launch_bounds__(64) void k_reduce(
    const float* __restrict__ loss, float* __restrict__ out)
{
    int lane = threadIdx.x;
    float v = (lane < N) ? loss[lane] : 0.f;
    for (int off = 32; off; off >>= 1) v += __shfl_xor(v, off);
    if (lane == 0) out[0] = v;
}

extern "C" void kernel_launch(void* const* d_in, const int* in_sizes, int n_in,
                              void* d_out, int out_size, void* d_ws, size_t ws_size,
                              hipStream_t stream) {
    const float* x       = (const float*)d_in[0];
    const int*   labels  = (const int*)d_in[1];
    const int*   in_len  = (const int*)d_in[2];
    const int*   lab_len = (const int*)d_in[3];
    float* out  = (float*)d_out;
    float* pp   = (float*)d_ws;                          // TN*ROWF floats
    float* coef = pp + (size_t)TN * ROWF + 256;          // N*256*768 floats
    float* loss = coef + (size_t)N * NPAIR * PAIRF + 8 * PAIRF;  // + DMA pad

    k_softmax_probs<<<TN / 4, 256, 0, stream>>>(x, labels, pp, coef);
    k_ctc_alpha<<<N, 64, 0, stream>>>(pp, coef, labels, in_len, lab_len, loss);
    k_reduce<<<1, 64, 0, stream>>>(loss, out);
}

// Round 11
// 92.639 us; speedup vs baseline: 13.1539x; 1.0691x over previous
//
#include <hip/hip_runtime.h>

#define LN2 0.6931471805599453f

constexpr int T = 512, N = 32, C = 4000, S = 64;
constexpr int TN   = T * N;
constexpr int ROWF = 68;          // padded pp row stride (272B, 16B-aligned)
constexpr int CT   = 16;          // timesteps per LDS chunk
constexpr int NC   = T / CT;      // 32 chunks

// ---------------- Kernel 1: row-normalized softmax probs ---------------------
// One wave per (t,n) row. Streaming logsumexp over C=4000; emit probabilities
// at the 65 needed classes, scaled by 2^{-e_t} (row max in [1,2)); e_t to ee[].
__global__ __launch_bounds__(256) void k_softmax_probs(
    const float* __restrict__ x, const int* __restrict__ labels,
    float* __restrict__ pp, float* __restrict__ ee)
{
    int row  = blockIdx.x * 4 + (threadIdx.x >> 6);   // row = t*N + n
    int lane = threadIdx.x & 63;
    const float*  rp  = x + (size_t)row * C;
    const float4* rp4 = reinterpret_cast<const float4*>(rp);

    float m = -INFINITY, s = 0.f;
    #pragma unroll
    for (int k = 0; k < 15; ++k) {                 // 960 of 1000 float4s
        float4 v = rp4[lane + 64 * k];
        float mv = fmaxf(fmaxf(v.x, v.y), fmaxf(v.z, v.w));
        float s4 = __expf(v.x - mv) + __expf(v.y - mv) +
                   __expf(v.z - mv) + __expf(v.w - mv);
        float nm = fmaxf(m, mv);
        s = s * __expf(m - nm) + s4 * __expf(mv - nm);
        m = nm;
    }
    if (lane < 40) {                               // tail 40 float4s
        float4 v = rp4[960 + lane];
        float mv = fmaxf(fmaxf(v.x, v.y), fmaxf(v.z, v.w));
        float s4 = __expf(v.x - mv) + __expf(v.y - mv) +
                   __expf(v.z - mv) + __expf(v.w - mv);
        float nm = fmaxf(m, mv);
        s = s * __expf(m - nm) + s4 * __expf(mv - nm);
        m = nm;
    }
    for (int off = 32; off; off >>= 1) {
        float om = __shfl_xor(m, off), os = __shfl_xor(s, off);
        float nm = fmaxf(m, om);
        s = s * __expf(m - nm) + os * __expf(om - nm);
        m = nm;
    }
    float logZ = m + __logf(s);

    int t = row >> 5, n = row & 31;                // row = t*N + n, N = 32
    int c  = labels[n * S + lane];
    float zb = rp[0];                              // blank logit (all lanes)
    float zl = rp[c];                              // label logit

    // row max over the 65 relevant entries -> exact pow2 normalizer
    float wm = zl;
    for (int off = 32; off; off >>= 1) wm = fmaxf(wm, __shfl_xor(wm, off));
    wm = fmaxf(wm, zb);
    float pm = __expf(wm - logZ);                  // row max prob
    int e = (int)(__float_as_uint(pm) >> 23) - 127;

    float* outp = pp + ((size_t)n * T + t) * ROWF;
    outp[1 + lane] = ldexpf(__expf(zl - logZ), -e);
    if (lane == 0) {
        outp[0] = ldexpf(__expf(zb - logZ), -e);
        ee[n * T + t] = (float)e;
    }
}

// ---------------- DPP helpers ------------------------------------------------
__device__ __forceinline__ float dpp_shr1_zero(float x) {
    int r = __builtin_amdgcn_update_dpp(0, __float_as_int(x),
                                        0x138 /*wave_shr:1*/, 0xf, 0xf, false);
    return __int_as_float(r);
}
template <int CTRL>
__device__ __forceinline__ float dpp_max_step(float x) {
    int t = __builtin_amdgcn_update_dpp(__float_as_int(x), __float_as_int(x),
                                        CTRL, 0xf, 0xf, false);
    return fmaxf(x, __int_as_float(t));
}
__device__ __forceinline__ float wave_max_bcast(float x) {
    x = dpp_max_step<0xB1>(x);    // xor 1
    x = dpp_max_step<0x4E>(x);    // xor 2
    x = dpp_max_step<0x141>(x);   // xor 4
    x = dpp_max_step<0x140>(x);   // xor 8
    x = dpp_max_step<0x142>(x);   // row_bcast15
    x = dpp_max_step<0x143>(x);   // row_bcast31
    return __int_as_float(__builtin_amdgcn_readlane(__float_as_int(x), 63));
}

// ---------------- Kernel 2: alpha recursion, one wave per n -----------------
// Chain = pure pair_steps; renorm correction kA is computed from a snapshot
// two windows back, with the DPP-max tree hand-interleaved between pairs
// (independent of the alpha chain). Row scaling (k1) keeps decay small.
__global__ __launch_bounds__(64) void k_ctc_alpha(
    const float* __restrict__ pp, const float* __restrict__ ee,
    const int* __restrict__ labels,
    const int* __restrict__ input_len, const int* __restrict__ label_len,
    float* __restrict__ loss_out)
{
    __shared__ __align__(16) float lds[2][CT][ROWF];   // 8.7 KB
    const int n = blockIdx.x, lane = threadIdx.x;
    const int Tin = input_len[n], Sl = label_len[n];
    const float* bp = pp + (size_t)n * T * ROWF;

    const int li   = labels[n * S + lane];
    const int lim1 = lane ? labels[n * S + lane - 1] : -1;
    const float skf  = (lane > 0 && li != 0 && li != lim1) ? 1.f : 0.f;
    const float skUf = dpp_shr1_zero(skf);
    const float skk  = skf * skUf;

    asm volatile("s_waitcnt vmcnt(0)" ::: "memory");   // drain scalar-side loads
    __builtin_amdgcn_sched_barrier(0);

    float a0 = 0.f, a1 = 0.f, aX = 0.f;
    int SH = 0, kA = 0;
    float gs = 0.f;

#define ISSUE(cc) do {                                                        \
    const float* cp_ = bp + (size_t)(cc) * CT * ROWF;                         \
    if (lane < 17) {                                                          \
        _Pragma("unroll")                                                     \
        for (int d_ = 0; d_ < CT; ++d_)                                       \
            __builtin_amdgcn_global_load_lds(cp_ + (size_t)d_ * ROWF + lane * 4, \
                                             &lds[(cc) & 1][d_][0], 16, 0, 0);\
    } } while (0)

// two composed timesteps (on-the-fly coefficients; off-chain algebra)
#define PAIRS(B, D) do {                                                      \
    const float* R0_ = &lds[B][D][0];                                         \
    const float* R1_ = &lds[B][(D) + 1][0];                                   \
    float cb1 = R0_[0], cl1 = R0_[1 + lane];                                  \
    float cb2 = R1_[0], cl2 = R1_[1 + lane];                                  \
    float clU = dpp_shr1_zero(cl1);                                           \
    float W   = clU * cl2;                                                    \
    float A   = cb1 * cb2;                                                    \
    float B_  = clU * cb2;                                                    \
    float Cc  = A + B_;                                                       \
    float D_  = skUf * B_;                                                    \
    float s1  = cb1 + cl1;                                                    \
    float E   = s1 * cl2;                                                     \
    float F   = cl1 * cl2;                                                    \
    float G   = skf * W;                                                      \
    float H   = fmaf(skf, F + W, cb1 * cl2);                                  \
    float I   = skk * W;                                                      \
    float Y0  = cl1 * cb2;                                                    \
    float Y1  = s1 * cb2;                                                     \
    float Y2  = skf * Y0;                                                     \
    float p1  = dpp_shr1_zero(a1);                                            \
    float p0  = dpp_shr1_zero(a0);                                            \
    float p2  = dpp_shr1_zero(p1);                                            \
    float n0  = fmaf(p0, B_, a0 * A) + fmaf(p2, D_, p1 * Cc);                 \
    float n1  = fmaf(a1, F, a0 * E) + fmaf(p2, I, fmaf(p1, H, p0 * G));       \
    float nX  = fmaf(a1, Y1, aX * A) + fmaf(p1, Y2, a0 * Y0);                 \
    a0 = n0; a1 = n1; aX = nX;                                                \
} while (0)

// 8-step window: apply kA (from snapshot 2 windows back), fresh snapshot,
// 4 pairs with the PREVIOUS snapshot's max-tree interleaved off-chain.
#define WINDOW4(B, D0) do {                                                   \
    a0 = ldexpf(a0, kA); a1 = ldexpf(a1, kA); aX = ldexpf(aX, kA);            \
    SH += kA;                                                                 \
    float gnow_ = fmaxf(fmaxf(a0, a1), aX);                                   \
    PAIRS(B, D0);                                                             \
    gs = dpp_max_step<0xB1>(gs);  gs = dpp_max_step<0x4E>(gs);                \
    PAIRS(B, (D0) + 2);                                                       \
    gs = dpp_max_step<0x141>(gs); gs = dpp_max_step<0x140>(gs);               \
    PAIRS(B, (D0) + 4);                                                       \
    gs = dpp_max_step<0x142>(gs); gs = dpp_max_step<0x143>(gs);               \
    PAIRS(B, (D0) + 6);                                                       \
    {   unsigned b_ = (unsigned)__builtin_amdgcn_readlane(__float_as_int(gs), 63); \
        int e_ = (int)(b_ >> 23) - 127;                                       \
        kA = (b_ == 0u) ? 0 : (105 - e_ - kA);                                \
    }                                                                         \
    gs = gnow_;                                                               \
} while (0)

    if (Tin == T) {
        // ---------------- hot path ----------------
        ISSUE(0); ISSUE(1);
        asm volatile("s_waitcnt vmcnt(16)" ::: "memory");   // chunk 0 landed
        __builtin_amdgcn_sched_barrier(0);
        a0 = (lane == 0) ? lds[0][0][0] : 0.f;
        a1 = (lane == 0 && Sl > 0) ? lds[0][0][1] : 0.f;
        {   // t = 1 single step
            float cb = lds[0][1][0], cl = lds[0][1][1 + lane];
            float p1 = dpp_shr1_zero(a1);
            float n0 = (a0 + p1) * cb;
            float n1 = fmaf(skf, p1, a0 + a1) * cl;
            float nX = (aX + a1) * cb;
            a0 = n0; a1 = n1; aX = nX;
        }
        PAIRS(0, 2); PAIRS(0, 4); PAIRS(0, 6);              // t = 2..7
        {   // direct renorm to anchor 105 (once, on-chain)
            float g = wave_max_bcast(fmaxf(fmaxf(a0, a1), aX));
            unsigned b = __float_as_uint(g);
            int k0 = (b == 0u) ? 0 : (105 - ((int)(b >> 23) - 127));
            a0 = ldexpf(a0, k0); a1 = ldexpf(a1, k0); aX = ldexpf(aX, k0);
            SH += k0; kA = 0;
            gs = fmaxf(fmaxf(a0, a1), aX);
        }
        WINDOW4(0, 8);                                      // t = 8..15
        __builtin_amdgcn_sched_barrier(0);
        ISSUE(2);
        for (int c = 1; c < NC; ++c) {
            if (c < NC - 1) { asm volatile("s_waitcnt vmcnt(16)" ::: "memory"); }
            else            { asm volatile("s_waitcnt vmcnt(0)"  ::: "memory"); }
            __builtin_amdgcn_sched_barrier(0);
            int buf = c & 1;
            WINDOW4(buf, 0);
            WINDOW4(buf, 8);
            if (c + 2 < NC) {
                __builtin_amdgcn_sched_barrier(0);
                ISSUE(c + 2);
            }
        }
    } else {
        // ---------------- generic fallback: per-step, freeze masking ----------
#define GSTEP(cc, dd) do {                                                    \
    float cb_ = lds[(cc) & 1][dd][0];                                         \
    float cl_ = lds[(cc) & 1][dd][1 + lane];                                  \
    float p1_ = dpp_shr1_zero(a1);                                            \
    float na0_ = (a0 + p1_) * cb_;                                            \
    float na1_ = fmaf(skf, p1_, a0 + a1) * cl_;                               \
    float naX_ = (aX + a1) * cb_;                                             \
    int t_ = (cc) * CT + (dd);                                                \
    bool act_ = (unsigned)(t_ - 1) < (unsigned)(Tin - 1);                     \
    a0 = act_ ? na0_ : a0;                                                    \
    a1 = act_ ? na1_ : a1;                                                    \
    aX = act_ ? naX_ : aX;                                                    \
    if (((dd) & 3) == 3) {                                                    \
        float g_ = wave_max_bcast(fmaxf(a0, fmaxf(a1, aX)));                  \
        unsigned b_ = __float_as_uint(g_);                                    \
        int k_ = (b_ == 0u) ? 0 : (100 - ((int)(b_ >> 23) - 127));            \
        a0 = ldexpf(a0, k_); a1 = ldexpf(a1, k_); aX = ldexpf(aX, k_);        \
        SH += k_;                                                             \
    }                                                                         \
} while (0)
        ISSUE(0); ISSUE(1);
        asm volatile("s_waitcnt vmcnt(16)" ::: "memory");
        __builtin_amdgcn_sched_barrier(0);
        a0 = (lane == 0) ? lds[0][0][0] : 0.f;
        a1 = (lane == 0 && Sl > 0) ? lds[0][0][1] : 0.f;
        #pragma unroll
        for (int d = 1; d < CT; ++d) GSTEP(0, d);
        __builtin_amdgcn_sched_barrier(0);
        ISSUE(2);
        for (int c = 1; c < NC; ++c) {
            if (c < NC - 1) { asm volatile("s_waitcnt vmcnt(16)" ::: "memory"); }
            else            { asm volatile("s_waitcnt vmcnt(0)"  ::: "memory"); }
            __builtin_amdgcn_sched_barrier(0);
            #pragma unroll
            for (int d = 0; d < CT; ++d) GSTEP(c, d);
            if (c + 2 < NC) {
                __builtin_amdgcn_sched_barrier(0);
                ISSUE(c + 2);
            }
        }
#undef GSTEP
    }
#undef WINDOW4
#undef PAIRS
#undef ISSUE

    // row-scale compensation: Sigma e_t over t < Tin (off-chain, once)
    float se = 0.f;
    #pragma unroll
    for (int j = 0; j < 8; ++j) {
        int idx = lane + 64 * j;
        float ev = ee[n * T + idx];
        se += (idx < Tin) ? ev : 0.f;
    }
    for (int off = 32; off; off >>= 1) se += __shfl_xor(se, off);

    // loss_n = -log(alpha[2*Sl] + alpha[2*Sl-1]), rescaled
    float a_last = (Sl >= S) ? __shfl(aX, 63) : __shfl(a0, Sl);
    float a_prev_raw = __shfl(a1, (Sl > 0) ? (Sl - 1) : 0);
    float a_prev = (Sl > 0) ? a_prev_raw : 0.f;
    if (lane == 0) {
        float sum  = a_last + a_prev;
        float ll2  = log2f(sum) - (float)SH + se;      // log2 P
        float loss = -ll2 * LN2;
        if (!(loss < 5e29f)) loss = 0.f;               // zero_infinity (+NaN)
        loss_out[n] = loss;
    }
}

// ---------------- Kernel 3: final sum ---------------------------------------
__global__ __launch_bounds__(64) void k_reduce(
    const float* __restrict__ loss, float* __restrict__ out)
{
    int lane = threadIdx.x;
    float v = (lane < N) ? loss[lane] : 0.f;
    for (int off = 32; off; off >>= 1) v += __shfl_xor(v, off);
    if (lane == 0) out[0] = v;
}

extern "C" void kernel_launch(void* const* d_in, const int* in_sizes, int n_in,
                              void* d_out, int out_size, void* d_ws, size_t ws_size,
                              hipStream_t stream) {
    const float* x       = (const float*)d_in[0];
    const int*   labels  = (const int*)d_in[1];
    const int*   in_len  = (const int*)d_in[2];
    const int*   lab_len = (const int*)d_in[3];
    float* out  = (float*)d_out;
    float* pp   = (float*)d_ws;                          // TN*ROWF floats
    float* ee   = pp + (size_t)TN * ROWF + 256;          // TN floats (row exps)
    float* loss = ee + TN;                               // N floats

    k_softmax_probs<<<TN / 4, 256, 0, stream>>>(x, labels, pp, ee);
    k_ctc_alpha<<<N, 64, 0, stream>>>(pp, ee, labels, in_len, lab_len, loss);
    k_reduce<<<1, 64, 0, stream>>>(loss, out);
}